// Round 9
// baseline (140.571 us; speedup 1.0000x reference)
//
#include <hip/hip_runtime.h>
#include <stdint.h>

#define NN 4096
#define MM 8192
#define DD 512
#define KT 8  // 512 / BK, BK = 64

typedef __bf16 bf16x8 __attribute__((ext_vector_type(8)));
typedef float f32x4 __attribute__((ext_vector_type(4)));
typedef float f32x16 __attribute__((ext_vector_type(16)));

__device__ __forceinline__ void load_lds16(const void* g, void* l) {
  // async global -> LDS, 16B/lane; LDS dest must be wave-uniform base + lane*16.
  __builtin_amdgcn_global_load_lds(
      (const __attribute__((address_space(1))) unsigned int*)g,
      (__attribute__((address_space(3))) unsigned int*)l, 16, 0, 0);
}

// VALU-pipe partial reduction (R7-verified correct): x += rot16(x, k).
template <int CTRL>
__device__ __forceinline__ float dpp_radd(float x) {
  int xi = __float_as_int(x);
  int mv = __builtin_amdgcn_update_dpp(xi, xi, CTRL, 0xF, 0xF, false);
  return x + __int_as_float(mv);
}
__device__ __forceinline__ float swz_add_xor16(float x) {
  int sv = __builtin_amdgcn_ds_swizzle(__float_as_int(x), 0x401F);
  return x + __int_as_float(sv);
}

// One wave per row. Lane l holds row elements [8l, 8l+8) (coalesced f32x4 x2).
// SV rows -> row-major bf16 chunks (LDS staging path, unchanged semantics).
// X rows  -> MFMA-A-fragment order:
//   Xf[(rg*32 + s)*64 + h*32 + r31] holds X[rg*32+r31][s*16 + h*8 .. +8)
//   (rg=r>>5, r31=r&31, s=l>>1, h=l&1) — exactly the 32x32x16 A-operand
//   lane mapping, so the GEMM loads A-frags with ONE coalesced 16B/lane read.
// Also: exact fp32 row-norms and out[]=IC init.
__global__ __launch_bounds__(256) void convert_norm_kernel(
    const float* __restrict__ X, const float* __restrict__ SV,
    bf16x8* __restrict__ Xf, bf16x8* __restrict__ SVb,
    float* __restrict__ x2, float* __restrict__ sv2,
    float* __restrict__ out, const float* __restrict__ IC) {
  int wid = blockIdx.x * 4 + (threadIdx.x >> 6);
  int lane = threadIdx.x & 63;
  const float* src;
  float* nrm;
  bool isX = (wid < NN);
  int r = isX ? wid : wid - NN;
  if (isX) {
    src = X + (size_t)r * DD;
    nrm = x2 + r;
    if (lane == 0) out[r] = IC[0];
  } else {
    src = SV + (size_t)r * DD;
    nrm = sv2 + r;
  }
  const f32x4* s = (const f32x4*)src;
  f32x4 a = s[2 * lane];      // elements 8l .. 8l+3
  f32x4 b = s[2 * lane + 1];  // elements 8l+4 .. 8l+7
  float sum = a.x * a.x + a.y * a.y + a.z * a.z + a.w * a.w +
              b.x * b.x + b.y * b.y + b.z * b.z + b.w * b.w;
  bf16x8 o;
  o[0] = (__bf16)a.x; o[1] = (__bf16)a.y; o[2] = (__bf16)a.z; o[3] = (__bf16)a.w;
  o[4] = (__bf16)b.x; o[5] = (__bf16)b.y; o[6] = (__bf16)b.z; o[7] = (__bf16)b.w;
  if (isX) {
    const int rg = r >> 5, r31 = r & 31;
    Xf[((size_t)(rg * 32 + (lane >> 1))) * 64 + (lane & 1) * 32 + r31] = o;
  } else {
    SVb[(size_t)r * 64 + lane] = o;
  }
#pragma unroll
  for (int m = 32; m >= 1; m >>= 1) sum += __shfl_xor(sum, m, 64);
  if (lane == 0) *nrm = sum;
}

// 128x128 tile, 4 waves (2x2), each wave 64x64 via 2x2 mfma_f32_32x32x16_bf16.
// A: DIRECT from global in fragment order (Xf) — one coalesced 16B/lane load
//    per frag; vmcnt-prefetchable across barriers (not ordered by s_barrier),
//    L1-shared between the two wave_m partners. No LDS round-trip for A.
// B: LDS double-buffer 2x16 KB (BK=64), R4's verified coalesced+swizzled
//    staging (kg = slot ^ (row&7)); stage kt+1 before computing kt; one
//    barrier per kt. Total LDS 32 KB -> 4 blocks/CU.
__global__ __launch_bounds__(256, 4) void rbf_gemm_kernel(
    const bf16x8* __restrict__ Xf, const bf16x8* __restrict__ SVb,
    const float* __restrict__ x2, const float* __restrict__ sv2,
    const float* __restrict__ DC, const float* __restrict__ gamma_p,
    float* __restrict__ out) {
  __shared__ bf16x8 Bs[2][1024];  // 2 x 16 KB (128 rows x 8 chunks, swizzled)

  const int t = threadIdx.x;
  const int lane = t & 63;
  const int wave = t >> 6;
  const int n0 = blockIdx.x * 128;
  const int m0 = blockIdx.y * 128;

  const int wave_m = wave & 1;   // m-dir of C
  const int wave_n = wave >> 1;  // n-dir of C
  const int l31 = lane & 31;
  const int lhi = lane >> 5;

  // B staging decomposition (chunk c = it*256 + t), R4-verified swizzle
  const int srow = t >> 3;   // rows 0..31 for it=0, +32 per it
  const int sslot = t & 7;

  // A fragment bases: rg0/rg1 = row-groups (32 rows) of this wave's sub-tile.
  // frag chunk idx = rg*2048 + sg*64 + lane, sg = kt*4 + ks.
  const int rgb = blockIdx.x * 4 + wave_n * 2;  // rg0 = rgb, rg1 = rgb+1
  const bf16x8* a0p = Xf + (size_t)rgb * 2048 + lane;
  const bf16x8* a1p = a0p + 2048;

  f32x16 acc[2][2];
#pragma unroll
  for (int i = 0; i < 2; ++i)
#pragma unroll
    for (int j = 0; j < 2; ++j)
#pragma unroll
      for (int r = 0; r < 16; ++r) acc[i][j][r] = 0.0f;

  // prologue: stage B kt=0 into buffer 0
#pragma unroll
  for (int it = 0; it < 4; ++it) {
    const int c = it * 256 + t;
    const int row = it * 32 + srow;
    const int kg = sslot ^ (row & 7);
    load_lds16(SVb + (size_t)(m0 + row) * 64 + kg, &Bs[0][c]);
  }
  __syncthreads();

#pragma unroll
  for (int kt = 0; kt < KT; ++kt) {
    const int cur = kt & 1;
    const int nxt = cur ^ 1;
    if (kt + 1 < KT) {  // stage B for kt+1 (in flight during compute below)
#pragma unroll
      for (int it = 0; it < 4; ++it) {
        const int c = it * 256 + t;
        const int row = it * 32 + srow;
        const int kg = sslot ^ (row & 7);
        load_lds16(SVb + (size_t)(m0 + row) * 64 + (kt + 1) * 8 + kg,
                   &Bs[nxt][c]);
      }
    }
    // compute kt: A-frags straight from global (compiler pipelines via vmcnt)
#pragma unroll
    for (int ks = 0; ks < 4; ++ks) {
      const int sg = kt * 4 + ks;
      bf16x8 af0 = a0p[(size_t)sg * 64];
      bf16x8 af1 = a1p[(size_t)sg * 64];
      const int kc = ks * 2 + lhi;        // B k-chunk 0..7
      const int sw = kc ^ (l31 & 7);
      const int rb = (wave_m * 64 + l31) * 8;
      bf16x8 bf0 = Bs[cur][rb + sw];
      bf16x8 bf1 = Bs[cur][rb + 256 + sw];  // +32 rows
      acc[0][0] = __builtin_amdgcn_mfma_f32_32x32x16_bf16(af0, bf0, acc[0][0], 0, 0, 0);
      acc[0][1] = __builtin_amdgcn_mfma_f32_32x32x16_bf16(af0, bf1, acc[0][1], 0, 0, 0);
      acc[1][0] = __builtin_amdgcn_mfma_f32_32x32x16_bf16(af1, bf0, acc[1][0], 0, 0, 0);
      acc[1][1] = __builtin_amdgcn_mfma_f32_32x32x16_bf16(af1, bf1, acc[1][1], 0, 0, 0);
    }
    __syncthreads();
  }

  // ---- epilogue (no barriers) ----
  const float g = gamma_p[0];
  const float c2 = g * 1.4426950408889634f;  // gamma * log2(e)

  float sv2v[2], dcv[2];
  const int colb = m0 + wave_m * 64 + l31;
  sv2v[0] = sv2[colb];
  dcv[0] = DC[colb];
  sv2v[1] = sv2[colb + 32];
  dcv[1] = DC[colb + 32];

#pragma unroll
  for (int i = 0; i < 2; ++i) {
    // C row = rowb + 8*g4 + r2, where reg = g4*4 + r2
    const int rowb = n0 + wave_n * 64 + i * 32 + 4 * lhi;
    float val[16];
#pragma unroll
    for (int g4 = 0; g4 < 4; ++g4) {
      f32x4 xv = *(const f32x4*)(x2 + rowb + 8 * g4);
#pragma unroll
      for (int r2 = 0; r2 < 4; ++r2) {
        const int reg = g4 * 4 + r2;
        float v = 0.0f;
#pragma unroll
        for (int j = 0; j < 2; ++j) {
          float d2 = xv[r2] + sv2v[j] - 2.0f * acc[i][j][reg];
          d2 = fmaxf(d2, 0.0f);
          v += exp2f(-c2 * d2) * dcv[j];
        }
        val[reg] = v;
      }
    }
    // reduce over 32 column-lanes: 4 DPP row-rotations (VALU) + ds_swizzle xor16
#pragma unroll
    for (int reg = 0; reg < 16; ++reg) {
      float v = val[reg];
      v = dpp_radd<0x121>(v);  // row_ror:1
      v = dpp_radd<0x122>(v);  // row_ror:2
      v = dpp_radd<0x124>(v);  // row_ror:4
      v = dpp_radd<0x128>(v);  // row_ror:8
      val[reg] = swz_add_xor16(v);
    }
    if (l31 == 0) {
#pragma unroll
      for (int g4 = 0; g4 < 4; ++g4)
#pragma unroll
        for (int r2 = 0; r2 < 4; ++r2)
          atomicAdd(&out[rowb + 8 * g4 + r2], val[g4 * 4 + r2]);
    }
  }
}

extern "C" void kernel_launch(void* const* d_in, const int* in_sizes, int n_in,
                              void* d_out, int out_size, void* d_ws, size_t ws_size,
                              hipStream_t stream) {
  const float* X = (const float*)d_in[0];
  const float* SV = (const float*)d_in[1];
  const float* DC = (const float*)d_in[2];
  const float* IC = (const float*)d_in[3];
  const float* gamma = (const float*)d_in[4];
  float* out = (float*)d_out;

  char* ws = (char*)d_ws;
  bf16x8* Xf = (bf16x8*)ws;                                   // 4 MB (frag order)
  bf16x8* SVb = (bf16x8*)(ws + (size_t)NN * DD * 2);          // 8 MB (row-major)
  float* x2 = (float*)(ws + (size_t)(NN + MM) * DD * 2);      // 16 KB
  float* sv2 = x2 + NN;                                       // 32 KB

  convert_norm_kernel<<<(NN + MM) / 4, 256, 0, stream>>>(X, SV, Xf, SVb, x2, sv2, out, IC);
  dim3 grid(NN / 128, MM / 128);
  rbf_gemm_kernel<<<grid, 256, 0, stream>>>(Xf, SVb, x2, sv2, DC, gamma, out);
}